// Round 10
// baseline (267.480 us; speedup 1.0000x reference)
//
#include <hip/hip_runtime.h>

// GCNN via FFT over the cyclic group C_256 — packed-row, 64KB-exact edition.
// 1 packed pair (2 batch rows) per block, 512 blocks x 512 threads.
// Zs[32][256] float2 = 65536 B exactly -> target 2 blocks/CU (4 waves/SIMD).
// Z = rowA + i*rowB; spectral GEMM acts on Z directly (complex-linear w/
// Hermitian weights, conj-trick partner bins share one weight load).
// Input spectrum: wave0 FFTs, mirrors IN REGISTERS (R5-verified gather),
// stashes into Zs row 31 as temp; row 31's real value written after barrier.
// GEMM: lane = (kp, fi-half, fo-half); fi halves combined via shfl_xor(,2).

#define NG 256
#define NLAYER 3

__device__ __forceinline__ int brv6(int x) { return (int)(__brev((unsigned)x) >> 26); }

// ---------------- LDS FFT machinery (used ONLY by gcnn_wfft) ----------------
__device__ __forceinline__ int swz(int a) {
  int h = a >> 4;
  return a ^ ((h ^ (h << 1)) & 15);
}

__device__ __forceinline__ void wave_fft256_lds(float2* __restrict__ s,
                                                const float2* __restrict__ tw,
                                                int lane) {
  asm volatile("s_waitcnt lgkmcnt(0)" ::: "memory");
  #pragma unroll
  for (int t = 0; t < 4; ++t) {
    int i = t * 64 + lane;
    int j = (int)(__brev((unsigned)i) >> 24);
    if (j > i) {
      float2 a = s[swz(i)]; float2 b = s[swz(j)];
      s[swz(i)] = b; s[swz(j)] = a;
    }
  }
  asm volatile("s_waitcnt lgkmcnt(0)" ::: "memory");
  #pragma unroll
  for (int st = 0; st < 8; ++st) {
    const int half = 1 << st;
    const int tshift = 7 - st;
    #pragma unroll
    for (int t = 0; t < 2; ++t) {
      int bf = t * 64 + lane;
      int off = bf & (half - 1);
      int blk = bf >> st;
      int i = (blk << (st + 1)) + off;
      int j = i + half;
      float2 wv = tw[swz(off << tshift)];
      float2 u = s[swz(i)];
      float2 v = s[swz(j)];
      float vr = v.x * wv.x - v.y * wv.y;
      float vi = v.x * wv.y + v.y * wv.x;
      s[swz(i)] = make_float2(u.x + vr, u.y + vi);
      s[swz(j)] = make_float2(u.x - vr, u.y - vi);
    }
    asm volatile("s_waitcnt lgkmcnt(0)" ::: "memory");
  }
}

// weight FFT prep. Ws_hat: full 256 positions; WeqM: positions 0..127;
// Weq128: bin 128. (Identical to proven R8/R9 prep.)
__global__ __launch_bounds__(256) void gcnn_wfft(
    const float* __restrict__ w_symm, const float* __restrict__ w_eq,
    float2* __restrict__ Ws_hat, float2* __restrict__ WeqM,
    float2* __restrict__ Weq128) {
  __shared__ float2 fbw[4][256];
  __shared__ float2 twl[256];
  const int tid = threadIdx.x;
  const int w = tid >> 6;
  const int lane = tid & 63;
  {
    float a = (float)tid * 0.0245436926f;  // 2*pi/256
    twl[swz(tid)] = make_float2(cosf(a), -sinf(a));
  }
  __syncthreads();
  const int task = blockIdx.x * 4 + w;  // 776*4 = 3104 tasks exactly
  if (task < 32) {
    const int f = task;
    for (int g = lane; g < 256; g += 64)
      fbw[w][swz(g)] = make_float2(w_symm[g * 32 + f], 0.f);
    wave_fft256_lds(&fbw[w][0], twl, lane);
    for (int k = lane; k < 256; k += 64) {
      int pos = brv6(k & 63) | (k & 192);
      Ws_hat[f * 256 + pos] = fbw[w][swz(k)];
    }
  } else {
    const int idx = task - 32;
    const int l = idx >> 10;
    const int fi = (idx >> 5) & 31;
    const int fo = idx & 31;
    for (int g = lane; g < 256; g += 64)
      fbw[w][swz(g)] = make_float2(w_eq[((size_t)(l * 256 + g) * 32 + fi) * 32 + fo] * (1.f / 256.f), 0.f);
    wave_fft256_lds(&fbw[w][0], twl, lane);
    for (int k = lane; k < 129; k += 64) {
      int sk = (k < 64) ? brv6(k) : ((k < 128) ? 64 + brv6(k - 64) : 128);
      if (sk < 128)
        WeqM[((size_t)((l * 32 + fi) * 128 + sk)) * 32 + fo] = fbw[w][swz(k)];
      else
        Weq128[(l * 32 + fi) * 32 + fo] = fbw[w][swz(k)];
    }
  }
}

// ---------------- register FFT machinery (verified rounds 4-9, absmax 0) ----------------
__device__ __forceinline__ float2 cadd(float2 a, float2 b) { return make_float2(a.x + b.x, a.y + b.y); }
__device__ __forceinline__ float2 csub(float2 a, float2 b) { return make_float2(a.x - b.x, a.y - b.y); }
__device__ __forceinline__ float2 cmul(float2 a, float2 b) {
  return make_float2(a.x * b.x - a.y * b.y, a.x * b.y + a.y * b.x);
}
__device__ __forceinline__ float2 cmulc(float2 a, float2 b) {  // a * conj(b)
  return make_float2(a.x * b.x + a.y * b.y, a.y * b.x - a.x * b.y);
}
__device__ __forceinline__ float2 shxor(float2 v, int m) {
  return make_float2(__shfl_xor(v.x, m), __shfl_xor(v.y, m));
}

// Forward: T {z[r]=x[4*lane+r]} -> S {z[r]=X[bitrev6(lane)+64r]}
__device__ __forceinline__ void fwd256(float2 z[4], const float2 tw[5],
                                       float2 u1, float2 u2, float2 u3, int lane) {
  #pragma unroll
  for (int s = 0; s < 6; ++s) {
    const int half = 32 >> s;
    const bool bot = (lane & half) != 0;
    #pragma unroll
    for (int r = 0; r < 4; ++r) {
      float2 o = shxor(z[r], half);
      float2 sum = cadd(z[r], o);
      float2 dif = csub(o, z[r]);
      float2 bo = (s < 5) ? cmul(dif, tw[s]) : dif;
      z[r] = bot ? bo : sum;
    }
  }
  z[1] = cmul(z[1], u1);
  z[2] = cmul(z[2], u2);
  z[3] = cmul(z[3], u3);
  float2 t0 = cadd(z[0], z[2]), t1 = cadd(z[1], z[3]);
  float2 t2 = csub(z[0], z[2]), t3 = csub(z[1], z[3]);
  z[0] = cadd(t0, t1);
  z[2] = csub(t0, t1);
  z[1] = make_float2(t2.x + t3.y, t2.y - t3.x);
  z[3] = make_float2(t2.x - t3.y, t2.y + t3.x);
}

// Inverse (unnormalized): S -> T
__device__ __forceinline__ void inv256(float2 z[4], const float2 tw[5],
                                       float2 u1, float2 u2, float2 u3, int lane) {
  float2 t0 = cadd(z[0], z[2]), t1 = cadd(z[1], z[3]);
  float2 t2 = csub(z[0], z[2]), t3 = csub(z[1], z[3]);
  z[0] = cadd(t0, t1);
  z[2] = csub(t0, t1);
  z[1] = make_float2(t2.x - t3.y, t2.y + t3.x);
  z[3] = make_float2(t2.x + t3.y, t2.y - t3.x);
  z[1] = cmulc(z[1], u1);
  z[2] = cmulc(z[2], u2);
  z[3] = cmulc(z[3], u3);
  #pragma unroll
  for (int s = 5; s >= 0; --s) {
    const int half = 32 >> s;
    const bool bot = (lane & half) != 0;
    #pragma unroll
    for (int r = 0; r < 4; ++r) {
      float2 m = (s < 5 && bot) ? cmulc(z[r], tw[s]) : z[r];
      float2 o = shxor(m, half);
      z[r] = bot ? csub(o, m) : cadd(o, m);
    }
  }
}

__device__ __forceinline__ float swishf(float y) { return y / (1.f + __expf(-y)); }

// ---------------- main fused kernel: 512 blocks x 512 threads, 1 pair (2 rows) ----------------
__global__ __launch_bounds__(512, 4) void gcnn_main(
    const float* __restrict__ x_in, const float* __restrict__ b_symm,
    const float* __restrict__ b_eq, const float2* __restrict__ Ws_hat,
    const float2* __restrict__ WeqM, const float2* __restrict__ Weq128,
    float* __restrict__ out) {
  __shared__ float2 Zs[32 * 256];   // [fi][pos], 65536 bytes EXACTLY

  const int tid = threadIdx.x;
  const int w = tid >> 6;
  const int lane = tid & 63;
  const int brev = brv6(lane);

  // per-lane FFT constants
  float2 tw[5];
  #pragma unroll
  for (int s = 0; s < 5; ++s) {
    const int half = 32 >> s;
    float ang = -0.09817477042468103871f * (float)((lane & (half - 1)) << s);
    __sincosf(ang, &tw[s].y, &tw[s].x);
  }
  float2 u1;
  {
    float ang = -0.02454369260617025968f * (float)brev;
    __sincosf(ang, &u1.y, &u1.x);
  }
  const float2 u2 = cmul(u1, u1);
  const float2 u3 = cmul(u2, u1);
  const int rbl = brv6((64 - brev) & 63);   // mirror lane (for lane != 0)

  // Phase 0a: wave0 packs 2 rows, FFTs, mirrors in regs, stashes into row 31
  if (w == 0) {
    const float* xa = x_in + (size_t)blockIdx.x * 2 * NG;
    float4 va = reinterpret_cast<const float4*>(xa)[lane];
    float4 vb = reinterpret_cast<const float4*>(xa + NG)[lane];
    float2 z[4] = {{va.x, vb.x}, {va.y, vb.y}, {va.z, vb.z}, {va.w, vb.w}};
    fwd256(z, tw, u1, u2, u3, lane);
    // mirrored spectrum mz[pos(lane,r)] = Zx[mirror position]
    float2 mz[4];
    #pragma unroll
    for (int r = 0; r < 4; ++r) {
      float2 g = make_float2(__shfl(z[3 - r].x, rbl), __shfl(z[3 - r].y, rbl));
      mz[r] = g;
    }
    if (lane == 0) {
      float2 own[4] = {z[0], z[1], z[2], z[3]};
      #pragma unroll
      for (int r = 0; r < 4; ++r) mz[r] = own[(4 - r) & 3];
    }
    #pragma unroll
    for (int r = 0; r < 4; ++r) Zs[31 * 256 + lane + (r << 6)] = mz[r];
  }
  __syncthreads();

  // Phase 0b: Z0[f][s] = ZxMirror[s] * WsHat[f][s] (+256*bs*(1+i) at s=0)
  {
    float2 keep[4];
    #pragma unroll
    for (int j = 0; j < 4; ++j) {
      const int f = w + 8 * j;
      const float bs = 256.f * b_symm[f];
      const float2* wsf = Ws_hat + f * 256;
      float2 o[4];
      #pragma unroll
      for (int r = 0; r < 4; ++r) {
        const int s = lane + (r << 6);
        float2 m = Zs[31 * 256 + s];
        o[r] = cmul(m, wsf[s]);
        if (s == 0) { o[r].x += bs; o[r].y += bs; }
      }
      if (f == 31) {
        #pragma unroll
        for (int r = 0; r < 4; ++r) keep[r] = o[r];
      } else {
        #pragma unroll
        for (int r = 0; r < 4; ++r) Zs[f * 256 + lane + (r << 6)] = o[r];
      }
    }
    __syncthreads();   // all reads of temp row 31 complete
    if (w == 7) {
      #pragma unroll
      for (int r = 0; r < 4; ++r) Zs[31 * 256 + lane + (r << 6)] = keep[r];
    }
  }
  __syncthreads();

  float outv0 = 0.f, outv1 = 0.f;  // only tid<2 uses at the end

  #pragma unroll 1
  for (int l = 0; l < NLAYER; ++l) {
    const bool last = (l == NLAYER - 1);

    // ---- spectral GEMM on packed Z: lane = (kp, fi-half, fo-half) ----
    {
      const int kp = tid >> 2;          // 0..127 (position = bin for kp<64? no: S layout)
      const int fh = (tid >> 1) & 1;    // fi half
      const int hf = tid & 1;           // fo half
      const int lq = kp & 63;
      int spart;
      if (lq == 0) spart = (kp == 0) ? 0 : 192;   // kp=0: dummy (bin0 self-conj)
      else spart = brv6((64 - brv6(lq)) & 63) + ((3 - (kp >> 6)) << 6);
      float2 alo[16], ahi[16];
      #pragma unroll
      for (int j = 0; j < 16; ++j) {
        alo[j] = make_float2(0.f, 0.f);
        ahi[j] = make_float2(0.f, 0.f);
      }
      #pragma unroll 2
      for (int f2 = 0; f2 < 16; ++f2) {
        const int fi = fh * 16 + f2;
        float2 h0 = Zs[fi * 256 + kp];
        float2 h1 = Zs[fi * 256 + spart];
        const float4* wp = reinterpret_cast<const float4*>(
            WeqM + ((size_t)((l * 32 + fi) * 128 + kp)) * 32 + hf * 16);
        #pragma unroll
        for (int q = 0; q < 8; ++q) {
          float4 v = wp[q];
          alo[2 * q].x     += h0.x * v.x - h0.y * v.y;
          alo[2 * q].y     += h0.x * v.y + h0.y * v.x;
          ahi[2 * q].x     += h1.x * v.x + h1.y * v.y;   // * conj(w)
          ahi[2 * q].y     += h1.y * v.x - h1.x * v.y;
          alo[2 * q + 1].x += h0.x * v.z - h0.y * v.w;
          alo[2 * q + 1].y += h0.x * v.w + h0.y * v.z;
          ahi[2 * q + 1].x += h1.x * v.z + h1.y * v.w;
          ahi[2 * q + 1].y += h1.y * v.z - h1.x * v.w;
        }
      }
      // combine fi halves across the (fh) lane pair; shfl is also the RAW fence
      #pragma unroll
      for (int j = 0; j < 16; ++j) {
        alo[j] = cadd(alo[j], shxor(alo[j], 2));
        ahi[j] = cadd(ahi[j], shxor(ahi[j], 2));
      }
      if (fh == 0) {
        if (kp == 0) {
          #pragma unroll
          for (int j = 0; j < 16; ++j) {
            float be = b_eq[l * 32 + hf * 16 + j];
            alo[j].x += be;
            alo[j].y += be;
          }
        }
        #pragma unroll
        for (int j = 0; j < 16; ++j) {
          Zs[(hf * 16 + j) * 256 + kp] = alo[j];
          if (kp != 0) Zs[(hf * 16 + j) * 256 + spart] = ahi[j];
        }
      }
      // position-128 (bin 128, self-conjugate) tail: wave0 lanes 0..31
      if (w == 0 && lane < 32) {
        const int fo = lane;
        float2 a = make_float2(0.f, 0.f);
        #pragma unroll 4
        for (int fi = 0; fi < 32; ++fi) {
          float2 h = Zs[fi * 256 + 128];
          float2 v = Weq128[(l * 32 + fi) * 32 + fo];
          a.x += h.x * v.x - h.y * v.y;
          a.y += h.x * v.y + h.y * v.x;
        }
        Zs[fo * 256 + 128] = a;
      }
    }
    __syncthreads();

    // ---- per feature: IFFT -> swish -> (FFT+store | reduce) ----
    float ls0 = 0.f, ls1 = 0.f;
    #pragma unroll 1
    for (int j = 0; j < 4; ++j) {
      const int f = w + 8 * j;
      float2* zrow = Zs + f * 256;
      float2 z[4];
      #pragma unroll
      for (int r = 0; r < 4; ++r) z[r] = zrow[lane + (r << 6)];
      inv256(z, tw, u1, u2, u3, lane);   // z[r] = (rowA[4lane+r], rowB[4lane+r])
      if (!last) {
        #pragma unroll
        for (int r = 0; r < 4; ++r) {
          z[r].x = swishf(z[r].x);
          z[r].y = swishf(z[r].y);
        }
        fwd256(z, tw, u1, u2, u3, lane);
        #pragma unroll
        for (int r = 0; r < 4; ++r) zrow[lane + (r << 6)] = z[r];
      } else {
        #pragma unroll
        for (int r = 0; r < 4; ++r) {
          ls0 += swishf(z[r].x);
          ls1 += swishf(z[r].y);
        }
      }
    }
    if (last) {
      #pragma unroll
      for (int m = 32; m >= 1; m >>= 1) {
        ls0 += __shfl_xor(ls0, m);
        ls1 += __shfl_xor(ls1, m);
      }
      __syncthreads();                 // all waves done READING Zs
      if (lane == 0) Zs[w] = make_float2(ls0, ls1);   // red overlay on row 0
    }
    __syncthreads();
  }

  if (tid < 2) {
    float s = 0.f;
    #pragma unroll
    for (int ww = 0; ww < 8; ++ww)
      s += (tid == 0) ? Zs[ww].x : Zs[ww].y;
    out[blockIdx.x * 2 + tid] = s * (1.f / 8192.f);
  }
}

extern "C" void kernel_launch(void* const* d_in, const int* in_sizes, int n_in,
                              void* d_out, int out_size, void* d_ws, size_t ws_size,
                              hipStream_t stream) {
  const float* x_in   = (const float*)d_in[0];
  // d_in[1] = perms, d_in[2] = group_algebra: structure hard-coded (cyclic group)
  const float* w_symm = (const float*)d_in[3];
  const float* b_symm = (const float*)d_in[4];
  const float* w_eq   = (const float*)d_in[5];
  const float* b_eq   = (const float*)d_in[6];
  float* out = (float*)d_out;

  float2* Ws_hat = (float2*)d_ws;                      // 32*256
  float2* WeqM   = Ws_hat + 32 * 256;                  // 3*32*128*32
  float2* Weq128 = WeqM + (size_t)3 * 32 * 128 * 32;   // 3*32*32  (~3.24 MB total)

  hipLaunchKernelGGL(gcnn_wfft, dim3(776), dim3(256), 0, stream,
                     w_symm, w_eq, Ws_hat, WeqM, Weq128);
  hipLaunchKernelGGL(gcnn_main, dim3(512), dim3(512), 0, stream,
                     x_in, b_symm, b_eq, Ws_hat, WeqM, Weq128, out);
}